// Round 9
// baseline (491.382 us; speedup 1.0000x reference)
//
#include <hip/hip_runtime.h>
#include <math.h>

#define BB 4
#define LL 1024
#define DIN 64
#define DD 512
#define HH 8
#define DH 64
#define NLAYER 3
#define DFF 2048
#define FEAT 530
#define FEATP 544
#define MM 4096

typedef float f32x4 __attribute__((ext_vector_type(4)));
typedef short s16x8 __attribute__((ext_vector_type(8)));

__device__ __forceinline__ unsigned short f2bf(float f) {
    unsigned int u = __float_as_uint(f);
    u += 0x7fffu + ((u >> 16) & 1u);
    return (unsigned short)(u >> 16);
}
__device__ __forceinline__ float bf2f(unsigned short u) {
    return __uint_as_float(((unsigned int)u) << 16);
}
__device__ __forceinline__ float gelu_exact(float x) {
    return 0.5f * x * (1.0f + erff(x * 0.7071067811865475f));
}
__device__ __forceinline__ float wave_reduce_sum(float v) {
    #pragma unroll
    for (int o = 32; o; o >>= 1) v += __shfl_down(v, o);
    return v;
}
__device__ __forceinline__ void gload16(const unsigned short* g, unsigned short* l) {
    __builtin_amdgcn_global_load_lds(
        (const __attribute__((address_space(1))) unsigned int*)g,
        (__attribute__((address_space(3))) unsigned int*)l, 16, 0, 0);
}

// ---------------- generic f32 -> bf16 convert ----------------
__global__ __launch_bounds__(256) void cvt_kernel(
    const float* __restrict__ in, unsigned short* __restrict__ out, int n)
{
    for (int i = blockIdx.x * 256 + threadIdx.x; i < n; i += gridDim.x * 256)
        out[i] = f2bf(in[i]);
}

// ---------------- cpe_w [512][530] f32 -> [512][544] bf16 (zero pad) ----------------
__global__ __launch_bounds__(256) void cpe_pad_kernel(
    const float* __restrict__ in, unsigned short* __restrict__ out)
{
    for (int i = blockIdx.x * 256 + threadIdx.x; i < DD * FEATP; i += gridDim.x * 256) {
        int r = i / FEATP, c = i - r * FEATP;
        out[i] = (c < FEAT) ? f2bf(in[(size_t)r * FEAT + c]) : 0;
    }
}

// ---------------- build Z[M][544] bf16: PE + raw + RBFs ----------------
__global__ __launch_bounds__(256) void build_z_kernel(
    const float* __restrict__ c_local, const float* __restrict__ c_sink,
    unsigned short* __restrict__ Z)
{
    int row = blockIdx.x;
    int b = row >> 10, l = row & 1023;
    int t = threadIdx.x;
    unsigned short* zr = Z + (size_t)row * FEATP;
    for (int d = t; d < DD; d += 256) {
        int i = d >> 1;
        float dv = expf((float)(2 * i) * (-0.017988946135618352f)); // -ln(1e4)/512
        float ang = (float)l * dv;
        zr[d] = f2bf((d & 1) ? cosf(ang) : sinf(ang));
    }
    if (t < 32) {
        float cl = c_local[(size_t)b * LL + l]; cl = fminf(fmaxf(cl, 0.f), 1.f);
        float cs = c_sink [(size_t)b * LL + l]; cs = fminf(fmaxf(cs, 0.f), 1.f);
        float v = 0.f;
        if (t == 0) v = cl;
        else if (t == 1) v = cs;
        else if (t < 10)  { float c = (float)(t - 2) * (1.0f / 7.0f);  float df = (cl - c) / 0.200001f; v = expf(-0.5f * df * df); }
        else if (t < 18)  { float c = (float)(t - 10) * (1.0f / 7.0f); float df = (cs - c) / 0.200001f; v = expf(-0.5f * df * df); }
        zr[512 + t] = (t < 18) ? f2bf(v) : 0;
    }
}

// ---------------- sink row ----------------
__global__ __launch_bounds__(256) void sink_kernel(
    const float* __restrict__ c_sink, const int* __restrict__ lengths,
    const float* __restrict__ beta_p, const float* __restrict__ floor_p,
    const float* __restrict__ gamma_p, float* __restrict__ srow)
{
    int i = blockIdx.x * 256 + threadIdx.x;
    int b = i >> 10, k = i & 1023;
    float beta = *beta_p, flr = *floor_p, gmm = *gamma_p;
    float cs = c_sink[i]; cs = fminf(fmaxf(cs, 0.f), 1.f);
    float v = beta * (flr + (1.f - flr) * powf(cs + 1e-6f, gmm));
    srow[i] = (k < lengths[b]) ? v : 0.f;
}

// ---------------- delay feature encoder: e[B,D] ----------------
__global__ __launch_bounds__(512) void delay_kernel(
    const float* __restrict__ delay, const float* __restrict__ w1, const float* __restrict__ b1,
    const float* __restrict__ w2, const float* __restrict__ b2,
    const float* __restrict__ lng, const float* __restrict__ lnb,
    float* __restrict__ e)
{
    int b = blockIdx.x;
    int t = threadIdx.x;
    __shared__ float g1[DD];
    __shared__ float red[16];
    float t1 = delay[b] * w1[t] + b1[t];
    g1[t] = gelu_exact(t1);
    __syncthreads();
    const float* wr = w2 + (size_t)t * DD;
    float s = b2[t];
    for (int j = 0; j < DD; j += 4) {
        float4 w4 = *(const float4*)(wr + j);
        s += w4.x * g1[j] + w4.y * g1[j+1] + w4.z * g1[j+2] + w4.w * g1[j+3];
    }
    float rs = wave_reduce_sum(s);
    float rss = wave_reduce_sum(s * s);
    int lane = t & 63, w = t >> 6;
    if (lane == 0) { red[w] = rs; red[8 + w] = rss; }
    __syncthreads();
    float mean = 0.f, msq = 0.f;
    #pragma unroll
    for (int i = 0; i < 8; ++i) { mean += red[i]; msq += red[8 + i]; }
    mean *= (1.0f / DD); msq *= (1.0f / DD);
    float rstd = rsqrtf(msq - mean * mean + 1e-5f);
    e[(size_t)b * DD + t] = (s - mean) * rstd * lng[t] + lnb[t];
}

// ---- templated MFMA GEMM ----
// MODE 0: f32 out ; 1: bf16 out ; 2: f32 out + resid ; 3: bf16 gelu ;
// MODE 4: bf16 out, bias indexed by ROW m (for V^T = Wv @ X^T + bv)
template<int BM, int BN, int FM, int FN, int WGN, int MODE>
__global__ __launch_bounds__(256) void gemm_t(
    const unsigned short* __restrict__ A, const unsigned short* __restrict__ W,
    const float* __restrict__ bias, const float* __restrict__ resid,
    float* __restrict__ outf, unsigned short* __restrict__ outb,
    int M, int N, int K)
{
    __shared__ __align__(16) unsigned short As[BM * 32];
    __shared__ __align__(16) unsigned short Ws[BN * 32];
    int bm = blockIdx.y * BM, bn = blockIdx.x * BN;
    int t = threadIdx.x;
    int lane = t & 63, wid = t >> 6;
    int wr = wid / WGN, wc = wid % WGN;
    int l15 = lane & 15, lg = lane >> 4;
    int srow = lane >> 2;
    int sc8 = ((lane & 3) ^ ((lane >> 2) & 3) ^ ((lane >> 4) & 3)) * 8;
    int chunk8 = (lg ^ (l15 & 3) ^ ((l15 >> 2) & 3)) * 8;

    f32x4 acc[FM][FN] = {};
    int nk = K >> 5;

    for (int ks = 0; ks < nk; ++ks) {
        int kb = ks * 32;
        #pragma unroll
        for (int i = 0; i < BM / 64; ++i) {
            int row = wid * (BM / 4) + i * 16 + srow;
            gload16(A + (size_t)(bm + row) * K + kb + sc8, &As[(wid * (BM / 64) + i) * 512]);
        }
        #pragma unroll
        for (int i = 0; i < BN / 64; ++i) {
            int row = wid * (BN / 4) + i * 16 + srow;
            gload16(W + (size_t)(bn + row) * K + kb + sc8, &Ws[(wid * (BN / 64) + i) * 512]);
        }
        __syncthreads();
        s16x8 af[FM], wf[FN];
        #pragma unroll
        for (int mi = 0; mi < FM; ++mi)
            af[mi] = *(const s16x8*)&As[(wr * FM * 16 + mi * 16 + l15) * 32 + chunk8];
        #pragma unroll
        for (int ni = 0; ni < FN; ++ni)
            wf[ni] = *(const s16x8*)&Ws[(wc * FN * 16 + ni * 16 + l15) * 32 + chunk8];
        #pragma unroll
        for (int mi = 0; mi < FM; ++mi)
            #pragma unroll
            for (int ni = 0; ni < FN; ++ni)
                acc[mi][ni] = __builtin_amdgcn_mfma_f32_16x16x32_bf16(af[mi], wf[ni], acc[mi][ni], 0, 0, 0);
        __syncthreads();
    }

    int rbase = (lane >> 4) * 4;
    #pragma unroll
    for (int mi = 0; mi < FM; ++mi) {
        #pragma unroll
        for (int ni = 0; ni < FN; ++ni) {
            int n = bn + wc * FN * 16 + ni * 16 + l15;
            float bzc = (MODE == 4) ? 0.f : bias[n];
            #pragma unroll
            for (int r2 = 0; r2 < 4; ++r2) {
                int m = bm + wr * FM * 16 + mi * 16 + rbase + r2;
                float v = acc[mi][ni][r2] + ((MODE == 4) ? bias[m] : bzc);
                size_t o = (size_t)m * N + n;
                if (MODE == 0)      outf[o] = v;
                else if (MODE == 1) outb[o] = f2bf(v);
                else if (MODE == 2) outf[o] = v + resid[o];
                else if (MODE == 3) outb[o] = f2bf(gelu_exact(v));
                else                outb[o] = f2bf(v);
            }
        }
    }
}

// ------------- MFMA flash attention: 1-D grid (XCD-swizzled), 4 waves -------------
// qk: [B*L][1024] bf16 (Q at 0, K at 512). Vt: [512][4096] bf16 = V^T per (h,d) row.
#define SK 72
#define SPB 72
__global__ __launch_bounds__(256) void attn_mfma(
    const unsigned short* __restrict__ qk, const unsigned short* __restrict__ Vt,
    const float* __restrict__ c_local, const float* __restrict__ srow,
    const int* __restrict__ lengths,
    const float* __restrict__ alpha_p,
    unsigned short* __restrict__ o)
{
    __shared__ __align__(16) unsigned short Ks[64 * SK];
    __shared__ __align__(16) unsigned short Vts[64 * SK];
    __shared__ __align__(16) unsigned short Psb[64 * SPB];

    // XCD swizzle: the 16 q-blocks sharing (b,h) land on one XCD
    int id = blockIdx.x;
    int swz = (id & 7) * 64 + (id >> 3);
    int q0 = (swz & 15) * 64;
    int hh = (swz >> 4) & 7;
    int b  = swz >> 7;

    int t  = threadIdx.x;
    int lane = t & 63, w = t >> 6;
    int l15 = lane & 15, lg = lane >> 4;
    int len = lengths[b];
    int nt = (len + 63) >> 6;
    int kt0 = q0 >> 6;
    bool sink_blk = (q0 == 0);
    const float alpha = *alpha_p;

    // Q fragments, pre-scaled by 1/8 (exact: exponent shift)
    const unsigned short* qrow = qk + (size_t)(b * LL + q0 + w * 16 + l15) * 1024 + hh * DH;
    s16x8 qf0 = *(const s16x8*)(qrow + lg * 8);
    s16x8 qf1 = *(const s16x8*)(qrow + 32 + lg * 8);
    #pragma unroll
    for (int j = 0; j < 8; ++j) {
        qf0[j] = (short)f2bf(bf2f((unsigned short)qf0[j]) * 0.125f);
        qf1[j] = (short)f2bf(bf2f((unsigned short)qf1[j]) * 0.125f);
    }

    float cm1[4], cp1[4];
    #pragma unroll
    for (int r2 = 0; r2 < 4; ++r2) {
        int qi = q0 + w * 16 + lg * 4 + r2;
        cm1[r2] = 0.f; cp1[r2] = 0.f;
        if (qi >= 1 && qi < len) {
            int src = (qi == 1 || qi == LL - 1) ? qi : qi - 1;
            cm1[r2] = alpha * c_local[(size_t)b * LL + src];
        }
        if (qi + 1 < LL && qi < len)
            cp1[r2] = alpha * c_local[(size_t)b * LL + qi + 1];
    }
    bool need_sink = (sink_blk && w == 0 && lg == 0);

    float m_run[4], l_run[4];
    f32x4 accO[4] = {};
    #pragma unroll
    for (int r2 = 0; r2 < 4; ++r2) { m_run[r2] = -1e30f; l_run[r2] = 0.f; }

    int sr = t >> 3, sc8 = (t & 7) * 8;
    const unsigned short* kbase = qk + (size_t)(b * LL) * 1024 + 512 + hh * DH;
    const unsigned short* vbase = Vt + (size_t)(hh * DH) * MM + b * LL;   // row d: +d*MM, col k

    uint4 pk0 = *(const uint4*)(kbase + (size_t)sr * 1024 + sc8);
    uint4 pk1 = *(const uint4*)(kbase + (size_t)(sr + 32) * 1024 + sc8);
    uint4 pv0 = *(const uint4*)(vbase + (size_t)sr * MM + sc8);
    uint4 pv1 = *(const uint4*)(vbase + (size_t)(sr + 32) * MM + sc8);

    for (int kt = 0; kt < nt; ++kt) {
        int k0 = kt * 64;
        *(uint4*)&Ks[sr * SK + sc8]         = pk0;
        *(uint4*)&Ks[(sr + 32) * SK + sc8]  = pk1;
        *(uint4*)&Vts[sr * SK + sc8]        = pv0;
        *(uint4*)&Vts[(sr + 32) * SK + sc8] = pv1;
        if (kt + 1 < nt) {
            int kn = k0 + 64;
            pk0 = *(const uint4*)(kbase + (size_t)(kn + sr) * 1024 + sc8);
            pk1 = *(const uint4*)(kbase + (size_t)(kn + sr + 32) * 1024 + sc8);
            pv0 = *(const uint4*)(vbase + (size_t)sr * MM + kn + sc8);
            pv1 = *(const uint4*)(vbase + (size_t)(sr + 32) * MM + kn + sc8);
        }
        __syncthreads();

        // S = Q K^T (pre-scaled)
        f32x4 accS[4] = {};
        #pragma unroll
        for (int ct = 0; ct < 4; ++ct) {
            s16x8 kf0 = *(const s16x8*)&Ks[(ct * 16 + l15) * SK + lg * 8];
            s16x8 kf1 = *(const s16x8*)&Ks[(ct * 16 + l15) * SK + 32 + lg * 8];
            accS[ct] = __builtin_amdgcn_mfma_f32_16x16x32_bf16(qf0, kf0, accS[ct], 0, 0, 0);
            accS[ct] = __builtin_amdgcn_mfma_f32_16x16x32_bf16(qf1, kf1, accS[ct], 0, 0, 0);
        }

        float m4[4] = { -1e30f, -1e30f, -1e30f, -1e30f };
        bool slow = sink_blk || (kt >= kt0 - 1 && kt <= kt0 + 1) || (k0 + 64 > len);
        if (!slow) {
            // fast tile: no bias, no mask — just the row max
            #pragma unroll
            for (int ct = 0; ct < 4; ++ct)
                #pragma unroll
                for (int r2 = 0; r2 < 4; ++r2)
                    m4[r2] = fmaxf(m4[r2], accS[ct][r2]);
        } else if (k0 + 64 <= len) {
            #pragma unroll
            for (int ct = 0; ct < 4; ++ct) {
                int k = k0 + ct * 16 + l15;
                float sink_ct = need_sink ? srow[(size_t)b * LL + k] : 0.f;
                #pragma unroll
                for (int r2 = 0; r2 < 4; ++r2) {
                    int qi = q0 + w * 16 + lg * 4 + r2;
                    float v = accS[ct][r2];
                    if (k == qi - 1) v += cm1[r2];
                    else if (k == qi + 1) v += cp1[r2];
                    if (r2 == 0) v += sink_ct;
                    accS[ct][r2] = v;
                    m4[r2] = fmaxf(m4[r2], v);
                }
            }
        } else {
            #pragma unroll
            for (int ct = 0; ct < 4; ++ct) {
                int k = k0 + ct * 16 + l15;
                bool maskk = (k >= len);
                float sink_ct = need_sink ? srow[(size_t)b * LL + k] : 0.f;
                #pragma unroll
                for (int r2 = 0; r2 < 4; ++r2) {
                    int qi = q0 + w * 16 + lg * 4 + r2;
                    float v = accS[ct][r2];
                    if (k == qi - 1) v += cm1[r2];
                    else if (k == qi + 1 && !maskk) v += cp1[r2];
                    if (r2 == 0) v += sink_ct;
                    if (maskk) v -= 10000.f;
                    accS[ct][r2] = v;
                    m4[r2] = fmaxf(m4[r2], v);
                }
            }
        }

        #pragma unroll
        for (int r2 = 0; r2 < 4; ++r2) {
            #pragma unroll
            for (int msk = 1; msk < 16; msk <<= 1) m4[r2] = fmaxf(m4[r2], __shfl_xor(m4[r2], msk));
            float mnew = fmaxf(m_run[r2], m4[r2]);
            float scl = __expf(m_run[r2] - mnew);
            m_run[r2] = mnew;
            float rowsum = 0.f;
            #pragma unroll
            for (int ct = 0; ct < 4; ++ct) {
                float p = __expf(accS[ct][r2] - mnew);
                rowsum += p;
                Psb[(w * 16 + lg * 4 + r2) * SPB + ct * 16 + l15] = f2bf(p);
            }
            #pragma unroll
            for (int msk = 1; msk < 16; msk <<= 1) rowsum += __shfl_xor(rowsum, msk);
            l_run[r2] = l_run[r2] * scl + rowsum;
            #pragma unroll
            for (int dt = 0; dt < 4; ++dt) accO[dt][r2] *= scl;
        }

        // O += P @ V (wave-local P rows; bf16 fragments straight from LDS)
        #pragma unroll
        for (int kk = 0; kk < 2; ++kk) {
            s16x8 pf = *(const s16x8*)&Psb[(w * 16 + l15) * SPB + kk * 32 + lg * 8];
            #pragma unroll
            for (int dt = 0; dt < 4; ++dt) {
                s16x8 vf = *(const s16x8*)&Vts[(dt * 16 + l15) * SK + kk * 32 + lg * 8];
                accO[dt] = __builtin_amdgcn_mfma_f32_16x16x32_bf16(pf, vf, accO[dt], 0, 0, 0);
            }
        }
        __syncthreads();
    }

    #pragma unroll
    for (int r2 = 0; r2 < 4; ++r2) {
        float inv = 1.f / l_run[r2];
        int qi = q0 + w * 16 + lg * 4 + r2;
        #pragma unroll
        for (int dt = 0; dt < 4; ++dt)
            o[(size_t)(b * LL + qi) * DD + hh * DH + dt * 16 + l15] = f2bf(accO[dt][r2] * inv);
    }
}

// ------ embed epilogue: h += e + mask?0:gain*LN(cpe_pre) ------
__global__ __launch_bounds__(256) void embed_ep_kernel(
    const float* __restrict__ cpe_pre, const float* __restrict__ e,
    const int* __restrict__ lengths,
    const float* __restrict__ cpe_g, const float* __restrict__ cpe_lb,
    const float* __restrict__ gain_p, float* __restrict__ h)
{
    int row = blockIdx.x;
    int b = row >> 10, l = row & 1023;
    int t = threadIdx.x;
    __shared__ float red[16];
    const float* cp = cpe_pre + (size_t)row * DD;
    float v0 = cp[t], v1 = cp[t + 256];
    float s = v0 + v1, ss = v0 * v0 + v1 * v1;
    float rs = wave_reduce_sum(s), rss = wave_reduce_sum(ss);
    int lane = t & 63, w = t >> 6;
    if (lane == 0) { red[w] = rs; red[8 + w] = rss; }
    __syncthreads();
    float mean = 0.f, msq = 0.f;
    #pragma unroll
    for (int i = 0; i < 4; ++i) { mean += red[i]; msq += red[8 + i]; }
    mean *= (1.0f / DD); msq *= (1.0f / DD);
    float rstd = rsqrtf(msq - mean * mean + 1e-5f);
    bool maskp = (l >= lengths[b]);
    float gain = *gain_p;
    float pe0 = maskp ? 0.f : gain * ((v0 - mean) * rstd * cpe_g[t] + cpe_lb[t]);
    float pe1 = maskp ? 0.f : gain * ((v1 - mean) * rstd * cpe_g[t + 256] + cpe_lb[t + 256]);
    h[(size_t)row * DD + t]       += e[(size_t)b * DD + t] + pe0;
    h[(size_t)row * DD + t + 256] += e[(size_t)b * DD + t + 256] + pe1;
}

// ---------------- LayerNorm f32 out (final) ----------------
__global__ __launch_bounds__(256) void ln_kernel(
    const float* __restrict__ in, float* __restrict__ out,
    const float* __restrict__ g, const float* __restrict__ bta)
{
    int row = blockIdx.x; int t = threadIdx.x;
    __shared__ float red[16];
    const float* xr = in + (size_t)row * DD;
    float2 v = ((const float2*)xr)[t];
    float s = v.x + v.y, ss = v.x * v.x + v.y * v.y;
    float rs = wave_reduce_sum(s), rss = wave_reduce_sum(ss);
    int lane = t & 63, w = t >> 6;
    if (lane == 0) { red[w] = rs; red[8 + w] = rss; }
    __syncthreads();
    float mean = 0.f, msq = 0.f;
    #pragma unroll
    for (int i = 0; i < 4; ++i) { mean += red[i]; msq += red[8 + i]; }
    mean *= (1.0f / DD); msq *= (1.0f / DD);
    float rstd = rsqrtf(msq - mean * mean + 1e-5f);
    float2 gg = ((const float2*)g)[t], bb = ((const float2*)bta)[t];
    float2 o;
    o.x = (v.x - mean) * rstd * gg.x + bb.x;
    o.y = (v.y - mean) * rstd * gg.y + bb.y;
    ((float2*)(out + (size_t)row * DD))[t] = o;
}

// ---------------- LayerNorm bf16 out ----------------
__global__ __launch_bounds__(256) void ln_bf16_kernel(
    const float* __restrict__ in, unsigned short* __restrict__ out,
    const float* __restrict__ g, const float* __restrict__ bta)
{
    int row = blockIdx.x; int t = threadIdx.x;
    __shared__ float red[16];
    const float* xr = in + (size_t)row * DD;
    float2 v = ((const float2*)xr)[t];
    float s = v.x + v.y, ss = v.x * v.x + v.y * v.y;
    float rs = wave_reduce_sum(s), rss = wave_reduce_sum(ss);
    int lane = t & 63, w = t >> 6;
    if (lane == 0) { red[w] = rs; red[8 + w] = rss; }
    __syncthreads();
    float mean = 0.f, msq = 0.f;
    #pragma unroll
    for (int i = 0; i < 4; ++i) { mean += red[i]; msq += red[8 + i]; }
    mean *= (1.0f / DD); msq *= (1.0f / DD);
    float rstd = rsqrtf(msq - mean * mean + 1e-5f);
    float2 gg = ((const float2*)g)[t], bb = ((const float2*)bta)[t];
    ushort2 o;
    o.x = f2bf((v.x - mean) * rstd * gg.x + bb.x);
    o.y = f2bf((v.y - mean) * rstd * gg.y + bb.y);
    ((ushort2*)(out + (size_t)row * DD))[t] = o;
}

extern "C" void kernel_launch(void* const* d_in, const int* in_sizes, int n_in,
                              void* d_out, int out_size, void* d_ws, size_t ws_size,
                              hipStream_t stream)
{
    const float* x          = (const float*)d_in[0];
    const int*   lengths    = (const int*)  d_in[1];
    const float* input_delay= (const float*)d_in[2];
    const float* c_local    = (const float*)d_in[3];
    const float* c_sink     = (const float*)d_in[4];
    const float* in_w       = (const float*)d_in[5];
    const float* in_b       = (const float*)d_in[6];
    const float* de_w1      = (const float*)d_in[7];
    const float* de_b1      = (const float*)d_in[8];
    const float* de_w2      = (const float*)d_in[9];
    const float* de_b2      = (const float*)d_in[10];
    const float* de_ln_g    = (const float*)d_in[11];
    const float* de_ln_b    = (const float*)d_in[12];
    const float* cpe_w      = (const float*)d_in[13];
    const float* cpe_b      = (const float*)d_in[14];
    const float* cpe_ln_g   = (const float*)d_in[15];
    const float* cpe_ln_b   = (const float*)d_in[16];
    const float* gain       = (const float*)d_in[17];
    const float* alpha      = (const float*)d_in[18];
    const float* beta       = (const float*)d_in[19];
    const float* floorp     = (const float*)d_in[20];
    const float* gammap     = (const float*)d_in[21];
    const float* inproj_w   = (const float*)d_in[22];
    const float* inproj_b   = (const float*)d_in[23];
    const float* outproj_w  = (const float*)d_in[24];
    const float* outproj_b  = (const float*)d_in[25];
    const float* ln1_g      = (const float*)d_in[26];
    const float* ln1_b      = (const float*)d_in[27];
    const float* ln2_g      = (const float*)d_in[28];
    const float* ln2_b      = (const float*)d_in[29];
    const float* ff_w1      = (const float*)d_in[30];
    const float* ff_b1      = (const float*)d_in[31];
    const float* ff_w2      = (const float*)d_in[32];
    const float* ff_b2      = (const float*)d_in[33];
    const float* out_ln_g   = (const float*)d_in[34];
    const float* out_ln_b   = (const float*)d_in[35];

    char* base = (char*)d_ws;
    float* h            = (float*)base;                               // 8 MB
    unsigned short* act1 = (unsigned short*)(base + 8u*1024*1024);    // 4 MB
    char* bigb          = base + 12u*1024*1024;                       // 16 MB shared region
    unsigned short* qkb  = (unsigned short*)bigb;                     // 8 MB (attn phase: Q,K)
    unsigned short* vtb  = (unsigned short*)(bigb + 12u*1024*1024);   // 4 MB (attn phase: V^T [512][4096])
    unsigned short* ffb  = (unsigned short*)bigb;                     // 16 MB (FF phase)
    unsigned short* Zb   = (unsigned short*)bigb;                     // 4.46 MB (embed phase)
    unsigned short* x_bf = (unsigned short*)(bigb + 5u*1024*1024);    // 0.5 MB
    float* cpe_pre       = (float*)(bigb + 8u*1024*1024);             // 8 MB
    unsigned short* w_inproj  = (unsigned short*)(base + 28u*1024*1024);
    unsigned short* w_outproj = w_inproj  + (size_t)3*1536*512;
    unsigned short* w_ff1     = w_outproj + (size_t)3*512*512;
    unsigned short* w_ff2     = w_ff1     + (size_t)3*2048*512;
    unsigned short* w_in      = w_ff2     + (size_t)3*512*2048;
    unsigned short* w_cpe     = w_in      + (size_t)512*64;
    float* e                  = (float*)(w_cpe + (size_t)512*544);
    float* srow               = e + (size_t)BB*DD;

    cvt_kernel<<<128, 256, 0, stream>>>(x, x_bf, MM * DIN);
    cvt_kernel<<<2048, 256, 0, stream>>>(inproj_w, w_inproj, 3 * 1536 * 512);
    cvt_kernel<<<1024, 256, 0, stream>>>(outproj_w, w_outproj, 3 * 512 * 512);
    cvt_kernel<<<2048, 256, 0, stream>>>(ff_w1, w_ff1, 3 * 2048 * 512);
    cvt_kernel<<<2048, 256, 0, stream>>>(ff_w2, w_ff2, 3 * 512 * 2048);
    cvt_kernel<<<64, 256, 0, stream>>>(in_w, w_in, 512 * 64);
    cpe_pad_kernel<<<1024, 256, 0, stream>>>(cpe_w, w_cpe);

    delay_kernel<<<BB, 512, 0, stream>>>(input_delay, de_w1, de_b1, de_w2, de_b2, de_ln_g, de_ln_b, e);
    build_z_kernel<<<MM, 256, 0, stream>>>(c_local, c_sink, Zb);
    sink_kernel<<<BB * LL / 256, 256, 0, stream>>>(c_sink, lengths, beta, floorp, gammap, srow);

    gemm_t<64, 64, 2, 2, 2, 0><<<dim3(DD / 64, MM / 64), 256, 0, stream>>>(
        x_bf, w_in, in_b, nullptr, h, nullptr, MM, DD, DIN);
    gemm_t<64, 64, 2, 2, 2, 0><<<dim3(DD / 64, MM / 64), 256, 0, stream>>>(
        Zb, w_cpe, cpe_b, nullptr, cpe_pre, nullptr, MM, DD, FEATP);
    embed_ep_kernel<<<MM, 256, 0, stream>>>(cpe_pre, e, lengths, cpe_ln_g, cpe_ln_b, gain, h);

    for (int i = 0; i < NLAYER; ++i) {
        const unsigned short* wqk = w_inproj + (size_t)i * 1536 * 512;          // Q,K rows [0,1024)
        const unsigned short* wv  = wqk + (size_t)1024 * 512;                   // V rows [1024,1536)
        ln_bf16_kernel<<<MM, 256, 0, stream>>>(h, act1, ln1_g + (size_t)i * DD, ln1_b + (size_t)i * DD);
        // QK: [4096][1024] bf16
        gemm_t<64, 128, 2, 4, 2, 1><<<dim3(1024 / 128, MM / 64), 256, 0, stream>>>(
            act1, wqk, inproj_b + (size_t)i * 1536, nullptr, nullptr, qkb, MM, 1024, DD);
        // V^T: [512][4096] bf16 = Wv @ act1^T + bv (row bias)
        gemm_t<64, 64, 2, 2, 2, 4><<<dim3(MM / 64, DD / 64), 256, 0, stream>>>(
            wv, act1, inproj_b + (size_t)i * 1536 + 1024, nullptr, nullptr, vtb, DD, MM, DD);
        attn_mfma<<<512, 256, 0, stream>>>(qkb, vtb, c_local, srow, lengths, alpha, act1);
        gemm_t<64, 64, 2, 2, 2, 2><<<dim3(DD / 64, MM / 64), 256, 0, stream>>>(
            act1, w_outproj + (size_t)i * 512 * 512, outproj_b + (size_t)i * DD,
            h, h, nullptr, MM, DD, DD);
        ln_bf16_kernel<<<MM, 256, 0, stream>>>(h, act1, ln2_g + (size_t)i * DD, ln2_b + (size_t)i * DD);
        gemm_t<128, 128, 4, 4, 2, 3><<<dim3(DFF / 128, MM / 128), 256, 0, stream>>>(
            act1, w_ff1 + (size_t)i * 2048 * 512, ff_b1 + (size_t)i * DFF,
            nullptr, nullptr, ffb, MM, DFF, DD);
        gemm_t<64, 64, 2, 2, 2, 2><<<dim3(DD / 64, MM / 64), 256, 0, stream>>>(
            ffb, w_ff2 + (size_t)i * 512 * 2048, ff_b2 + (size_t)i * DD,
            h, h, nullptr, MM, DD, DFF);
    }
    ln_kernel<<<MM, 256, 0, stream>>>(h, (float*)d_out, out_ln_g, out_ln_b);
}

// Round 10
// 458.796 us; speedup vs baseline: 1.0710x; 1.0710x over previous
//
#include <hip/hip_runtime.h>
#include <math.h>

#define BB 4
#define LL 1024
#define DIN 64
#define DD 512
#define HH 8
#define DH 64
#define NLAYER 3
#define DFF 2048
#define FEAT 530
#define FEATP 576
#define MM 4096

typedef float f32x4 __attribute__((ext_vector_type(4)));
typedef short s16x8 __attribute__((ext_vector_type(8)));

__device__ __forceinline__ unsigned short f2bf(float f) {
    unsigned int u = __float_as_uint(f);
    u += 0x7fffu + ((u >> 16) & 1u);
    return (unsigned short)(u >> 16);
}
__device__ __forceinline__ float bf2f(unsigned short u) {
    return __uint_as_float(((unsigned int)u) << 16);
}
__device__ __forceinline__ float gelu_exact(float x) {
    return 0.5f * x * (1.0f + erff(x * 0.7071067811865475f));
}
__device__ __forceinline__ float wave_reduce_sum(float v) {
    #pragma unroll
    for (int o = 32; o; o >>= 1) v += __shfl_down(v, o);
    return v;
}
__device__ __forceinline__ void gload16(const unsigned short* g, unsigned short* l) {
    __builtin_amdgcn_global_load_lds(
        (const __attribute__((address_space(1))) unsigned int*)g,
        (__attribute__((address_space(3))) unsigned int*)l, 16, 0, 0);
}

// ---------------- generic f32 -> bf16 convert ----------------
__global__ __launch_bounds__(256) void cvt_kernel(
    const float* __restrict__ in, unsigned short* __restrict__ out, int n)
{
    for (int i = blockIdx.x * 256 + threadIdx.x; i < n; i += gridDim.x * 256)
        out[i] = f2bf(in[i]);
}

// ---------------- cpe_w [512][530] f32 -> [512][576] bf16 (zero pad) ----------------
__global__ __launch_bounds__(256) void cpe_pad_kernel(
    const float* __restrict__ in, unsigned short* __restrict__ out)
{
    for (int i = blockIdx.x * 256 + threadIdx.x; i < DD * FEATP; i += gridDim.x * 256) {
        int r = i / FEATP, c = i - r * FEATP;
        out[i] = (c < FEAT) ? f2bf(in[(size_t)r * FEAT + c]) : 0;
    }
}

// ---------------- build Z[M][576] bf16: PE + raw + RBFs + zero pad ----------------
__global__ __launch_bounds__(256) void build_z_kernel(
    const float* __restrict__ c_local, const float* __restrict__ c_sink,
    unsigned short* __restrict__ Z)
{
    int row = blockIdx.x;
    int b = row >> 10, l = row & 1023;
    int t = threadIdx.x;
    unsigned short* zr = Z + (size_t)row * FEATP;
    for (int d = t; d < DD; d += 256) {
        int i = d >> 1;
        float dv = expf((float)(2 * i) * (-0.017988946135618352f)); // -ln(1e4)/512
        float ang = (float)l * dv;
        zr[d] = f2bf((d & 1) ? cosf(ang) : sinf(ang));
    }
    if (t < 64) {
        float cl = c_local[(size_t)b * LL + l]; cl = fminf(fmaxf(cl, 0.f), 1.f);
        float cs = c_sink [(size_t)b * LL + l]; cs = fminf(fmaxf(cs, 0.f), 1.f);
        float v = 0.f;
        if (t == 0) v = cl;
        else if (t == 1) v = cs;
        else if (t < 10)  { float c = (float)(t - 2) * (1.0f / 7.0f);  float df = (cl - c) / 0.200001f; v = expf(-0.5f * df * df); }
        else if (t < 18)  { float c = (float)(t - 10) * (1.0f / 7.0f); float df = (cs - c) / 0.200001f; v = expf(-0.5f * df * df); }
        zr[512 + t] = (t < 18) ? f2bf(v) : 0;
    }
}

// ---------------- sink row ----------------
__global__ __launch_bounds__(256) void sink_kernel(
    const float* __restrict__ c_sink, const int* __restrict__ lengths,
    const float* __restrict__ beta_p, const float* __restrict__ floor_p,
    const float* __restrict__ gamma_p, float* __restrict__ srow)
{
    int i = blockIdx.x * 256 + threadIdx.x;
    int b = i >> 10, k = i & 1023;
    float beta = *beta_p, flr = *floor_p, gmm = *gamma_p;
    float cs = c_sink[i]; cs = fminf(fmaxf(cs, 0.f), 1.f);
    float v = beta * (flr + (1.f - flr) * powf(cs + 1e-6f, gmm));
    srow[i] = (k < lengths[b]) ? v : 0.f;
}

// ---------------- delay feature encoder: e[B,D] ----------------
__global__ __launch_bounds__(512) void delay_kernel(
    const float* __restrict__ delay, const float* __restrict__ w1, const float* __restrict__ b1,
    const float* __restrict__ w2, const float* __restrict__ b2,
    const float* __restrict__ lng, const float* __restrict__ lnb,
    float* __restrict__ e)
{
    int b = blockIdx.x;
    int t = threadIdx.x;
    __shared__ float g1[DD];
    __shared__ float red[16];
    float t1 = delay[b] * w1[t] + b1[t];
    g1[t] = gelu_exact(t1);
    __syncthreads();
    const float* wr = w2 + (size_t)t * DD;
    float s = b2[t];
    for (int j = 0; j < DD; j += 4) {
        float4 w4 = *(const float4*)(wr + j);
        s += w4.x * g1[j] + w4.y * g1[j+1] + w4.z * g1[j+2] + w4.w * g1[j+3];
    }
    float rs = wave_reduce_sum(s);
    float rss = wave_reduce_sum(s * s);
    int lane = t & 63, w = t >> 6;
    if (lane == 0) { red[w] = rs; red[8 + w] = rss; }
    __syncthreads();
    float mean = 0.f, msq = 0.f;
    #pragma unroll
    for (int i = 0; i < 8; ++i) { mean += red[i]; msq += red[8 + i]; }
    mean *= (1.0f / DD); msq *= (1.0f / DD);
    float rstd = rsqrtf(msq - mean * mean + 1e-5f);
    e[(size_t)b * DD + t] = (s - mean) * rstd * lng[t] + lnb[t];
}

// ---- templated MFMA GEMM, BK=64 (2 MFMA k-steps per staged tile) ----
// LDS rows are 64 shorts (128 B). Dest linear; source chunk pre-swizzled by
// c ^ (lane>>3); fragment phys chunk = (lg + 4*kk) ^ (row&7), row&7 == l15&7.
// MODE 0: f32 ; 1: bf16 ; 2: f32 + resid ; 3: bf16 gelu ; 4: bf16, bias by ROW
template<int BM, int BN, int FM, int FN, int WGN, int MODE>
__global__ __launch_bounds__(256) void gemm_t(
    const unsigned short* __restrict__ A, const unsigned short* __restrict__ W,
    const float* __restrict__ bias, const float* __restrict__ resid,
    float* __restrict__ outf, unsigned short* __restrict__ outb,
    int M, int N, int K)
{
    __shared__ __align__(16) unsigned short As[BM * 64];
    __shared__ __align__(16) unsigned short Ws[BN * 64];
    int bm = blockIdx.y * BM, bn = blockIdx.x * BN;
    int t = threadIdx.x;
    int lane = t & 63, wid = t >> 6;
    int wr = wid / WGN, wc = wid % WGN;
    int l15 = lane & 15, lg = lane >> 4;
    int sr = lane >> 3;                        // 0..7 (row within one gload instr)
    int sc = ((lane & 7) ^ sr) * 8;            // pre-swizzled source chunk (shorts)
    int ph0 = (lg ^ (l15 & 7)) * 8;            // phys chunk for k-step 0
    int ph1 = ((lg + 4) ^ (l15 & 7)) * 8;      // phys chunk for k-step 1

    f32x4 acc[FM][FN] = {};
    int nk = K >> 6;

    for (int ks = 0; ks < nk; ++ks) {
        int kb = ks * 64;
        #pragma unroll
        for (int i = 0; i < BM / 32; ++i) {
            int row = wid * (BM / 4) + i * 8 + sr;
            gload16(A + (size_t)(bm + row) * K + kb + sc, &As[(wid * (BM / 4) + i * 8) * 64]);
        }
        #pragma unroll
        for (int i = 0; i < BN / 32; ++i) {
            int row = wid * (BN / 4) + i * 8 + sr;
            gload16(W + (size_t)(bn + row) * K + kb + sc, &Ws[(wid * (BN / 4) + i * 8) * 64]);
        }
        __syncthreads();
        s16x8 af0[FM], af1[FM], wf0[FN], wf1[FN];
        #pragma unroll
        for (int mi = 0; mi < FM; ++mi) {
            int row = wr * FM * 16 + mi * 16 + l15;
            af0[mi] = *(const s16x8*)&As[row * 64 + ph0];
            af1[mi] = *(const s16x8*)&As[row * 64 + ph1];
        }
        #pragma unroll
        for (int ni = 0; ni < FN; ++ni) {
            int row = wc * FN * 16 + ni * 16 + l15;
            wf0[ni] = *(const s16x8*)&Ws[row * 64 + ph0];
            wf1[ni] = *(const s16x8*)&Ws[row * 64 + ph1];
        }
        #pragma unroll
        for (int mi = 0; mi < FM; ++mi)
            #pragma unroll
            for (int ni = 0; ni < FN; ++ni) {
                acc[mi][ni] = __builtin_amdgcn_mfma_f32_16x16x32_bf16(af0[mi], wf0[ni], acc[mi][ni], 0, 0, 0);
                acc[mi][ni] = __builtin_amdgcn_mfma_f32_16x16x32_bf16(af1[mi], wf1[ni], acc[mi][ni], 0, 0, 0);
            }
        __syncthreads();
    }

    int rbase = (lane >> 4) * 4;
    #pragma unroll
    for (int mi = 0; mi < FM; ++mi) {
        #pragma unroll
        for (int ni = 0; ni < FN; ++ni) {
            int n = bn + wc * FN * 16 + ni * 16 + l15;
            float bzc = (MODE == 4) ? 0.f : bias[n];
            #pragma unroll
            for (int r2 = 0; r2 < 4; ++r2) {
                int m = bm + wr * FM * 16 + mi * 16 + rbase + r2;
                float v = acc[mi][ni][r2] + ((MODE == 4) ? bias[m] : bzc);
                size_t o = (size_t)m * N + n;
                if (MODE == 0)      outf[o] = v;
                else if (MODE == 1) outb[o] = f2bf(v);
                else if (MODE == 2) outf[o] = v + resid[o];
                else if (MODE == 3) outb[o] = f2bf(gelu_exact(v));
                else                outb[o] = f2bf(v);
            }
        }
    }
}

// ------------- MFMA flash attention: double-buffered K/V, 1 barrier/tile -------------
// qk: [B*L][1024] bf16 (Q at 0, K at 512). Vt: [512][4096] bf16 = V^T per (h,d) row.
#define SK 72
#define SPB 72
__global__ __launch_bounds__(256) void attn_mfma(
    const unsigned short* __restrict__ qk, const unsigned short* __restrict__ Vt,
    const float* __restrict__ c_local, const float* __restrict__ srow,
    const int* __restrict__ lengths,
    const float* __restrict__ alpha_p,
    unsigned short* __restrict__ o)
{
    __shared__ __align__(16) unsigned short Ks[2][64 * SK];
    __shared__ __align__(16) unsigned short Vts[2][64 * SK];
    __shared__ __align__(16) unsigned short Psb[64 * SPB];

    // XCD swizzle: the 16 q-blocks sharing (b,h) land on one XCD
    int id = blockIdx.x;
    int swz = (id & 7) * 64 + (id >> 3);
    int q0 = (swz & 15) * 64;
    int hh = (swz >> 4) & 7;
    int b  = swz >> 7;

    int t  = threadIdx.x;
    int lane = t & 63, w = t >> 6;
    int l15 = lane & 15, lg = lane >> 4;
    int len = lengths[b];
    int nt = (len + 63) >> 6;
    int kt0 = q0 >> 6;
    bool sink_blk = (q0 == 0);
    const float alpha = *alpha_p;

    // Q fragments, pre-scaled by 1/8 (exact: exponent shift)
    const unsigned short* qrow = qk + (size_t)(b * LL + q0 + w * 16 + l15) * 1024 + hh * DH;
    s16x8 qf0 = *(const s16x8*)(qrow + lg * 8);
    s16x8 qf1 = *(const s16x8*)(qrow + 32 + lg * 8);
    #pragma unroll
    for (int j = 0; j < 8; ++j) {
        qf0[j] = (short)f2bf(bf2f((unsigned short)qf0[j]) * 0.125f);
        qf1[j] = (short)f2bf(bf2f((unsigned short)qf1[j]) * 0.125f);
    }

    float cm1[4], cp1[4];
    #pragma unroll
    for (int r2 = 0; r2 < 4; ++r2) {
        int qi = q0 + w * 16 + lg * 4 + r2;
        cm1[r2] = 0.f; cp1[r2] = 0.f;
        if (qi >= 1 && qi < len) {
            int src = (qi == 1 || qi == LL - 1) ? qi : qi - 1;
            cm1[r2] = alpha * c_local[(size_t)b * LL + src];
        }
        if (qi + 1 < LL && qi < len)
            cp1[r2] = alpha * c_local[(size_t)b * LL + qi + 1];
    }
    bool need_sink = (sink_blk && w == 0 && lg == 0);

    float m_run[4], l_run[4];
    f32x4 accO[4] = {};
    #pragma unroll
    for (int r2 = 0; r2 < 4; ++r2) { m_run[r2] = -1e30f; l_run[r2] = 0.f; }

    int sr = t >> 3, sc8 = (t & 7) * 8;
    const unsigned short* kbase = qk + (size_t)(b * LL) * 1024 + 512 + hh * DH;
    const unsigned short* vbase = Vt + (size_t)(hh * DH) * MM + b * LL;   // row d: +d*MM, col k

    // prefetch tile 0 and stage into buf 0
    uint4 pk0 = *(const uint4*)(kbase + (size_t)sr * 1024 + sc8);
    uint4 pk1 = *(const uint4*)(kbase + (size_t)(sr + 32) * 1024 + sc8);
    uint4 pv0 = *(const uint4*)(vbase + (size_t)sr * MM + sc8);
    uint4 pv1 = *(const uint4*)(vbase + (size_t)(sr + 32) * MM + sc8);
    *(uint4*)&Ks[0][sr * SK + sc8]         = pk0;
    *(uint4*)&Ks[0][(sr + 32) * SK + sc8]  = pk1;
    *(uint4*)&Vts[0][sr * SK + sc8]        = pv0;
    *(uint4*)&Vts[0][(sr + 32) * SK + sc8] = pv1;
    __syncthreads();

    int cur = 0;
    for (int kt = 0; kt < nt; ++kt) {
        int k0 = kt * 64;
        bool pre = (kt + 1 < nt);
        if (pre) {
            int kn = k0 + 64;
            pk0 = *(const uint4*)(kbase + (size_t)(kn + sr) * 1024 + sc8);
            pk1 = *(const uint4*)(kbase + (size_t)(kn + sr + 32) * 1024 + sc8);
            pv0 = *(const uint4*)(vbase + (size_t)sr * MM + kn + sc8);
            pv1 = *(const uint4*)(vbase + (size_t)(sr + 32) * MM + kn + sc8);
        }

        // S = Q K^T (pre-scaled)
        f32x4 accS[4] = {};
        #pragma unroll
        for (int ct = 0; ct < 4; ++ct) {
            s16x8 kf0 = *(const s16x8*)&Ks[cur][(ct * 16 + l15) * SK + lg * 8];
            s16x8 kf1 = *(const s16x8*)&Ks[cur][(ct * 16 + l15) * SK + 32 + lg * 8];
            accS[ct] = __builtin_amdgcn_mfma_f32_16x16x32_bf16(qf0, kf0, accS[ct], 0, 0, 0);
            accS[ct] = __builtin_amdgcn_mfma_f32_16x16x32_bf16(qf1, kf1, accS[ct], 0, 0, 0);
        }

        float m4[4] = { -1e30f, -1e30f, -1e30f, -1e30f };
        bool slow = sink_blk || (kt >= kt0 - 1 && kt <= kt0 + 1) || (k0 + 64 > len);
        if (!slow) {
            #pragma unroll
            for (int ct = 0; ct < 4; ++ct)
                #pragma unroll
                for (int r2 = 0; r2 < 4; ++r2)
                    m4[r2] = fmaxf(m4[r2], accS[ct][r2]);
        } else if (k0 + 64 <= len) {
            #pragma unroll
            for (int ct = 0; ct < 4; ++ct) {
                int k = k0 + ct * 16 + l15;
                float sink_ct = need_sink ? srow[(size_t)b * LL + k] : 0.f;
                #pragma unroll
                for (int r2 = 0; r2 < 4; ++r2) {
                    int qi = q0 + w * 16 + lg * 4 + r2;
                    float v = accS[ct][r2];
                    if (k == qi - 1) v += cm1[r2];
                    else if (k == qi + 1) v += cp1[r2];
                    if (r2 == 0) v += sink_ct;
                    accS[ct][r2] = v;
                    m4[r2] = fmaxf(m4[r2], v);
                }
            }
        } else {
            #pragma unroll
            for (int ct = 0; ct < 4; ++ct) {
                int k = k0 + ct * 16 + l15;
                bool maskk = (k >= len);
                float sink_ct = need_sink ? srow[(size_t)b * LL + k] : 0.f;
                #pragma unroll
                for (int r2 = 0; r2 < 4; ++r2) {
                    int qi = q0 + w * 16 + lg * 4 + r2;
                    float v = accS[ct][r2];
                    if (k == qi - 1) v += cm1[r2];
                    else if (k == qi + 1 && !maskk) v += cp1[r2];
                    if (r2 == 0) v += sink_ct;
                    if (maskk) v -= 10000.f;
                    accS[ct][r2] = v;
                    m4[r2] = fmaxf(m4[r2], v);
                }
            }
        }

        #pragma unroll
        for (int r2 = 0; r2 < 4; ++r2) {
            #pragma unroll
            for (int msk = 1; msk < 16; msk <<= 1) m4[r2] = fmaxf(m4[r2], __shfl_xor(m4[r2], msk));
            float mnew = fmaxf(m_run[r2], m4[r2]);
            float scl = __expf(m_run[r2] - mnew);
            m_run[r2] = mnew;
            float rowsum = 0.f;
            #pragma unroll
            for (int ct = 0; ct < 4; ++ct) {
                float p = __expf(accS[ct][r2] - mnew);
                rowsum += p;
                Psb[(w * 16 + lg * 4 + r2) * SPB + ct * 16 + l15] = f2bf(p);
            }
            #pragma unroll
            for (int msk = 1; msk < 16; msk <<= 1) rowsum += __shfl_xor(rowsum, msk);
            l_run[r2] = l_run[r2] * scl + rowsum;
            #pragma unroll
            for (int dt = 0; dt < 4; ++dt) accO[dt][r2] *= scl;
        }

        // O += P @ V (wave-local P rows; Psb needs no barrier)
        #pragma unroll
        for (int kk = 0; kk < 2; ++kk) {
            s16x8 pf = *(const s16x8*)&Psb[(w * 16 + l15) * SPB + kk * 32 + lg * 8];
            #pragma unroll
            for (int dt = 0; dt < 4; ++dt) {
                s16x8 vf = *(const s16x8*)&Vts[cur][(dt * 16 + l15) * SK + kk * 32 + lg * 8];
                accO[dt] = __builtin_amdgcn_mfma_f32_16x16x32_bf16(pf, vf, accO[dt], 0, 0, 0);
            }
        }

        // stage next tile into the other buffer (nobody reads it until after barrier)
        if (pre) {
            int nxt = cur ^ 1;
            *(uint4*)&Ks[nxt][sr * SK + sc8]         = pk0;
            *(uint4*)&Ks[nxt][(sr + 32) * SK + sc8]  = pk1;
            *(uint4*)&Vts[nxt][sr * SK + sc8]        = pv0;
            *(uint4*)&Vts[nxt][(sr + 32) * SK + sc8] = pv1;
        }
        __syncthreads();
        cur ^= 1;
    }

    #pragma unroll
    for (int r2 = 0; r2 < 4; ++r2) {
        float inv = 1.f / l_run[r2];
        int qi = q0 + w * 16 + lg * 4 + r2;
        #pragma unroll
        for (int dt = 0; dt < 4; ++dt)
            o[(size_t)(b * LL + qi) * DD + hh * DH + dt * 16 + l15] = f2bf(accO[dt][r2] * inv);
    }
}

// ------ embed epilogue: h += e + mask?0:gain*LN(cpe_pre) ------
__global__ __launch_bounds__(256) void embed_ep_kernel(
    const float* __restrict__ cpe_pre, const float* __restrict__ e,
    const int* __restrict__ lengths,
    const float* __restrict__ cpe_g, const float* __restrict__ cpe_lb,
    const float* __restrict__ gain_p, float* __restrict__ h)
{
    int row = blockIdx.x;
    int b = row >> 10, l = row & 1023;
    int t = threadIdx.x;
    __shared__ float red[16];
    const float* cp = cpe_pre + (size_t)row * DD;
    float v0 = cp[t], v1 = cp[t + 256];
    float s = v0 + v1, ss = v0 * v0 + v1 * v1;
    float rs = wave_reduce_sum(s), rss = wave_reduce_sum(ss);
    int lane = t & 63, w = t >> 6;
    if (lane == 0) { red[w] = rs; red[8 + w] = rss; }
    __syncthreads();
    float mean = 0.f, msq = 0.f;
    #pragma unroll
    for (int i = 0; i < 4; ++i) { mean += red[i]; msq += red[8 + i]; }
    mean *= (1.0f / DD); msq *= (1.0f / DD);
    float rstd = rsqrtf(msq - mean * mean + 1e-5f);
    bool maskp = (l >= lengths[b]);
    float gain = *gain_p;
    float pe0 = maskp ? 0.f : gain * ((v0 - mean) * rstd * cpe_g[t] + cpe_lb[t]);
    float pe1 = maskp ? 0.f : gain * ((v1 - mean) * rstd * cpe_g[t + 256] + cpe_lb[t + 256]);
    h[(size_t)row * DD + t]       += e[(size_t)b * DD + t] + pe0;
    h[(size_t)row * DD + t + 256] += e[(size_t)b * DD + t + 256] + pe1;
}

// ---------------- LayerNorm f32 out (final) ----------------
__global__ __launch_bounds__(256) void ln_kernel(
    const float* __restrict__ in, float* __restrict__ out,
    const float* __restrict__ g, const float* __restrict__ bta)
{
    int row = blockIdx.x; int t = threadIdx.x;
    __shared__ float red[16];
    const float* xr = in + (size_t)row * DD;
    float2 v = ((const float2*)xr)[t];
    float s = v.x + v.y, ss = v.x * v.x + v.y * v.y;
    float rs = wave_reduce_sum(s), rss = wave_reduce_sum(ss);
    int lane = t & 63, w = t >> 6;
    if (lane == 0) { red[w] = rs; red[8 + w] = rss; }
    __syncthreads();
    float mean = 0.f, msq = 0.f;
    #pragma unroll
    for (int i = 0; i < 4; ++i) { mean += red[i]; msq += red[8 + i]; }
    mean *= (1.0f / DD); msq *= (1.0f / DD);
    float rstd = rsqrtf(msq - mean * mean + 1e-5f);
    float2 gg = ((const float2*)g)[t], bb = ((const float2*)bta)[t];
    float2 o;
    o.x = (v.x - mean) * rstd * gg.x + bb.x;
    o.y = (v.y - mean) * rstd * gg.y + bb.y;
    ((float2*)(out + (size_t)row * DD))[t] = o;
}

// ---------------- LayerNorm bf16 out ----------------
__global__ __launch_bounds__(256) void ln_bf16_kernel(
    const float* __restrict__ in, unsigned short* __restrict__ out,
    const float* __restrict__ g, const float* __restrict__ bta)
{
    int row = blockIdx.x; int t = threadIdx.x;
    __shared__ float red[16];
    const float* xr = in + (size_t)row * DD;
    float2 v = ((const float2*)xr)[t];
    float s = v.x + v.y, ss = v.x * v.x + v.y * v.y;
    float rs = wave_reduce_sum(s), rss = wave_reduce_sum(ss);
    int lane = t & 63, w = t >> 6;
    if (lane == 0) { red[w] = rs; red[8 + w] = rss; }
    __syncthreads();
    float mean = 0.f, msq = 0.f;
    #pragma unroll
    for (int i = 0; i < 4; ++i) { mean += red[i]; msq += red[8 + i]; }
    mean *= (1.0f / DD); msq *= (1.0f / DD);
    float rstd = rsqrtf(msq - mean * mean + 1e-5f);
    float2 gg = ((const float2*)g)[t], bb = ((const float2*)bta)[t];
    ushort2 o;
    o.x = f2bf((v.x - mean) * rstd * gg.x + bb.x);
    o.y = f2bf((v.y - mean) * rstd * gg.y + bb.y);
    ((ushort2*)(out + (size_t)row * DD))[t] = o;
}

extern "C" void kernel_launch(void* const* d_in, const int* in_sizes, int n_in,
                              void* d_out, int out_size, void* d_ws, size_t ws_size,
                              hipStream_t stream)
{
    const float* x          = (const float*)d_in[0];
    const int*   lengths    = (const int*)  d_in[1];
    const float* input_delay= (const float*)d_in[2];
    const float* c_local    = (const float*)d_in[3];
    const float* c_sink     = (const float*)d_in[4];
    const float* in_w       = (const float*)d_in[5];
    const float* in_b       = (const float*)d_in[6];
    const float* de_w1      = (const float*)d_in[7];
    const float* de_b1      = (const float*)d_in[8];
    const float* de_w2      = (const float*)d_in[9];
    const float* de_b2      = (const float*)d_in[10];
    const float* de_ln_g    = (const float*)d_in[11];
    const float* de_ln_b    = (const float*)d_in[12];
    const float* cpe_w      = (const float*)d_in[13];
    const float* cpe_b      = (const float*)d_in[14];
    const float* cpe_ln_g   = (const float*)d_in[15];
    const float* cpe_ln_b   = (const float*)d_in[16];
    const float* gain       = (const float*)d_in[17];
    const float* alpha      = (const float*)d_in[18];
    const float* beta       = (const float*)d_in[19];
    const float* floorp     = (const float*)d_in[20];
    const float* gammap     = (const float*)d_in[21];
    const float* inproj_w   = (const float*)d_in[22];
    const float* inproj_b   = (const float*)d_in[23];
    const float* outproj_w  = (const float*)d_in[24];
    const float* outproj_b  = (const float*)d_in[25];
    const float* ln1_g      = (const float*)d_in[26];
    const float* ln1_b      = (const float*)d_in[27];
    const float* ln2_g      = (const float*)d_in[28];
    const float* ln2_b      = (const float*)d_in[29];
    const float* ff_w1      = (const float*)d_in[30];
    const float* ff_b1      = (const float*)d_in[31];
    const float* ff_w2      = (const float*)d_in[32];
    const float* ff_b2      = (const float*)d_in[33];
    const float* out_ln_g   = (const float*)d_in[34];
    const float* out_ln_b   = (const float*)d_in[35];

    char* base = (char*)d_ws;
    float* h            = (float*)base;                               // 8 MB
    unsigned short* act1 = (unsigned short*)(base + 8u*1024*1024);    // 4 MB
    char* bigb          = base + 12u*1024*1024;                       // 16 MB shared region
    unsigned short* qkb  = (unsigned short*)bigb;                     // 8 MB (attn phase: Q,K)
    unsigned short* vtb  = (unsigned short*)(bigb + 12u*1024*1024);   // 4 MB (attn phase: V^T [512][4096])
    unsigned short* ffb  = (unsigned short*)bigb;                     // 16 MB (FF phase)
    unsigned short* Zb   = (unsigned short*)bigb;                     // 4.7 MB (embed phase)
    unsigned short* x_bf = (unsigned short*)(bigb + 5u*1024*1024);    // 0.5 MB
    float* cpe_pre       = (float*)(bigb + 8u*1024*1024);             // 8 MB
    unsigned short* w_inproj  = (unsigned short*)(base + 28u*1024*1024);
    unsigned short* w_outproj = w_inproj  + (size_t)3*1536*512;
    unsigned short* w_ff1     = w_outproj + (size_t)3*512*512;
    unsigned short* w_ff2     = w_ff1     + (size_t)3*2048*512;
    unsigned short* w_in      = w_ff2     + (size_t)3*512*2048;
    unsigned short* w_cpe     = w_in      + (size_t)512*64;
    float* e                  = (float*)(w_cpe + (size_t)512*FEATP);
    float* srow               = e + (size_t)BB*DD;

    cvt_kernel<<<128, 256, 0, stream>>>(x, x_bf, MM * DIN);
    cvt_kernel<<<2048, 256, 0, stream>>>(inproj_w, w_inproj, 3 * 1536 * 512);
    cvt_kernel<<<1024, 256, 0, stream>>>(outproj_w, w_outproj, 3 * 512 * 512);
    cvt_kernel<<<2048, 256, 0, stream>>>(ff_w1, w_ff1, 3 * 2048 * 512);
    cvt_kernel<<<2048, 256, 0, stream>>>(ff_w2, w_ff2, 3 * 512 * 2048);
    cvt_kernel<<<64, 256, 0, stream>>>(in_w, w_in, 512 * 64);
    cpe_pad_kernel<<<1024, 256, 0, stream>>>(cpe_w, w_cpe);

    delay_kernel<<<BB, 512, 0, stream>>>(input_delay, de_w1, de_b1, de_w2, de_b2, de_ln_g, de_ln_b, e);
    build_z_kernel<<<MM, 256, 0, stream>>>(c_local, c_sink, Zb);
    sink_kernel<<<BB * LL / 256, 256, 0, stream>>>(c_sink, lengths, beta, floorp, gammap, srow);

    gemm_t<64, 64, 2, 2, 2, 0><<<dim3(DD / 64, MM / 64), 256, 0, stream>>>(
        x_bf, w_in, in_b, nullptr, h, nullptr, MM, DD, DIN);
    gemm_t<64, 64, 2, 2, 2, 0><<<dim3(DD / 64, MM / 64), 256, 0, stream>>>(
        Zb, w_cpe, cpe_b, nullptr, cpe_pre, nullptr, MM, DD, FEATP);
    embed_ep_kernel<<<MM, 256, 0, stream>>>(cpe_pre, e, lengths, cpe_ln_g, cpe_ln_b, gain, h);

    for (int i = 0; i < NLAYER; ++i) {
        const unsigned short* wqk = w_inproj + (size_t)i * 1536 * 512;          // Q,K rows [0,1024)
        const unsigned short* wv  = wqk + (size_t)1024 * 512;                   // V rows [1024,1536)
        ln_bf16_kernel<<<MM, 256, 0, stream>>>(h, act1, ln1_g + (size_t)i * DD, ln1_b + (size_t)i * DD);
        // QK: [4096][1024] bf16
        gemm_t<64, 128, 2, 4, 2, 1><<<dim3(1024 / 128, MM / 64), 256, 0, stream>>>(
            act1, wqk, inproj_b + (size_t)i * 1536, nullptr, nullptr, qkb, MM, 1024, DD);
        // V^T: [512][4096] bf16 = Wv @ act1^T + bv (row bias)
        gemm_t<64, 64, 2, 2, 2, 4><<<dim3(MM / 64, DD / 64), 256, 0, stream>>>(
            wv, act1, inproj_b + (size_t)i * 1536 + 1024, nullptr, nullptr, vtb, DD, MM, DD);
        attn_mfma<<<512, 256, 0, stream>>>(qkb, vtb, c_local, srow, lengths, alpha, act1);
        gemm_t<64, 64, 2, 2, 2, 2><<<dim3(DD / 64, MM / 64), 256, 0, stream>>>(
            act1, w_outproj + (size_t)i * 512 * 512, outproj_b + (size_t)i * DD,
            h, h, nullptr, MM, DD, DD);
        ln_bf16_kernel<<<MM, 256, 0, stream>>>(h, act1, ln2_g + (size_t)i * DD, ln2_b + (size_t)i * DD);
        gemm_t<128, 128, 4, 4, 2, 3><<<dim3(DFF / 128, MM / 128), 256, 0, stream>>>(
            act1, w_ff1 + (size_t)i * 2048 * 512, ff_b1 + (size_t)i * DFF,
            nullptr, nullptr, ffb, MM, DFF, DD);
        gemm_t<64, 64, 2, 2, 2, 2><<<dim3(DD / 64, MM / 64), 256, 0, stream>>>(
            ffb, w_ff2 + (size_t)i * 512 * 2048, ff_b2 + (size_t)i * DD,
            h, h, nullptr, MM, DD, DFF);
    }
    ln_kernel<<<MM, 256, 0, stream>>>(h, (float*)d_out, out_ln_g, out_ln_b);
}